// Round 2
// baseline (1410.062 us; speedup 1.0000x reference)
//
#include <hip/hip_runtime.h>
#include <hip/hip_bf16.h>

#define N_NODES 131072
#define N_EDGES 524288
#define DHID    128
#define DIN     256

typedef __attribute__((ext_vector_type(8))) short short8;
typedef __attribute__((ext_vector_type(4))) float floatx4;

__device__ inline short bf16_rne(float f) {
    union { float f; unsigned u; } v; v.f = f;
    unsigned r = v.u + 0x7FFF + ((v.u >> 16) & 1);
    return (short)(r >> 16);
}
__device__ inline float bf16_to_f(short s) {
    union { unsigned u; float f; } v; v.u = ((unsigned)(unsigned short)s) << 16;
    return v.f;
}

// ---------------- CSR build ----------------

__global__ __launch_bounds__(256) void count_edges(const int* __restrict__ dst,
                                                   int* __restrict__ counts) {
    int e = blockIdx.x * 256 + threadIdx.x;
    atomicAdd(&counts[dst[e]], 1);
}

__global__ __launch_bounds__(256) void scan1(const int* __restrict__ counts,
                                             int* __restrict__ offsets,
                                             int* __restrict__ bsums) {
    __shared__ int s[256];
    int i = blockIdx.x * 256 + threadIdx.x;
    int v = counts[i];
    s[threadIdx.x] = v;
    __syncthreads();
    for (int d = 1; d < 256; d <<= 1) {
        int t = (threadIdx.x >= d) ? s[threadIdx.x - d] : 0;
        __syncthreads();
        s[threadIdx.x] += t;
        __syncthreads();
    }
    offsets[i] = s[threadIdx.x] - v;
    if (threadIdx.x == 255) bsums[blockIdx.x] = s[255];
}

__global__ __launch_bounds__(512) void scan2(int* __restrict__ bsums) {
    __shared__ int s[512];
    int v = bsums[threadIdx.x];
    s[threadIdx.x] = v;
    __syncthreads();
    for (int d = 1; d < 512; d <<= 1) {
        int t = (threadIdx.x >= d) ? s[threadIdx.x - d] : 0;
        __syncthreads();
        s[threadIdx.x] += t;
        __syncthreads();
    }
    bsums[threadIdx.x] = s[threadIdx.x] - v;
}

// scan3: finalize offsets/cursor/dinv AND histogram node degrees for bucketing
__global__ __launch_bounds__(256) void scan3(const int* __restrict__ counts,
                                             int* __restrict__ offsets,
                                             int* __restrict__ cursor,
                                             float* __restrict__ dinv,
                                             const int* __restrict__ bsums,
                                             int* __restrict__ bhist) {
    int i = blockIdx.x * 256 + threadIdx.x;
    int off = offsets[i] + bsums[blockIdx.x];
    offsets[i] = off;
    cursor[i]  = off;
    int c = counts[i];
    dinv[i] = rsqrtf((float)(c + 1));
    atomicAdd(&bhist[c < 63 ? c : 63], 1);
}

// 64-bucket exclusive scan (one block, LDS)
__global__ __launch_bounds__(64) void bucket_scan(int* __restrict__ bhist,
                                                  int* __restrict__ bcur) {
    __shared__ int s[64];
    int v = bhist[threadIdx.x];
    s[threadIdx.x] = v;
    __syncthreads();
    for (int d = 1; d < 64; d <<= 1) {
        int t = (threadIdx.x >= d) ? s[threadIdx.x - d] : 0;
        __syncthreads();
        s[threadIdx.x] += t;
        __syncthreads();
    }
    bcur[threadIdx.x] = s[threadIdx.x] - v;
}

// counting-sort nodes by degree -> perm (waves then see uniform cnt)
__global__ __launch_bounds__(256) void bucket_scatter(const int* __restrict__ counts,
                                                      int* __restrict__ bcur,
                                                      int* __restrict__ perm) {
    int i = blockIdx.x * 256 + threadIdx.x;
    int c = counts[i];
    int p = atomicAdd(&bcur[c < 63 ? c : 63], 1);
    perm[p] = i;
}

// packed CSR entry: {src, bits(dinv[src])} — no dependent per-edge dinv gather
__global__ __launch_bounds__(256) void fill_csr(const int* __restrict__ src,
                                                const int* __restrict__ dst,
                                                int* __restrict__ cursor,
                                                const float* __restrict__ dinv,
                                                int2* __restrict__ csr) {
    int e = blockIdx.x * 256 + threadIdx.x;
    int d = dst[e];
    int s = src[e];
    int p = atomicAdd(&cursor[d], 1);
    csr[p] = make_int2(s, __float_as_int(dinv[s]));
}

// ---------------- fp32 -> bf16 conversions (once per call) ----------------

__global__ __launch_bounds__(256) void convert_weights(const float* __restrict__ Wn,
                                                       const float* __restrict__ W1,
                                                       const float* __restrict__ W2,
                                                       short* __restrict__ Wnb,
                                                       short* __restrict__ W1b,
                                                       short* __restrict__ W2b) {
    int i = blockIdx.x * 256 + threadIdx.x;          // 65536 total
    if (i < 32768)      Wnb[i] = bf16_rne(Wn[i]);
    else if (i < 49152) W1b[i - 32768] = bf16_rne(W1[i - 32768]);
    else                W2b[i - 49152] = bf16_rne(W2[i - 49152]);
}

__global__ __launch_bounds__(256) void convert_emb(const float* __restrict__ in,
                                                   short* __restrict__ outb) {
    size_t i = (size_t)(blockIdx.x * 256 + threadIdx.x) * 8;   // 32000*256 = 8192000
    float4 v0 = *(const float4*)&in[i];
    float4 v1 = *(const float4*)&in[i + 4];
    short8 o;
    o[0] = bf16_rne(v0.x); o[1] = bf16_rne(v0.y);
    o[2] = bf16_rne(v0.z); o[3] = bf16_rne(v0.w);
    o[4] = bf16_rne(v1.x); o[5] = bf16_rne(v1.y);
    o[6] = bf16_rne(v1.z); o[7] = bf16_rne(v1.w);
    *(short8*)&outb[i] = o;
}

// ---------------- embed GEMM: out[i][:] = embb[tok[i]] @ Wn^T + bn ----------------

__global__ __launch_bounds__(256) void gemm_embed(const short* __restrict__ Ab,
                                                  const int* __restrict__ tok,
                                                  const short* __restrict__ Wb,
                                                  const float* __restrict__ bias,
                                                  short* __restrict__ out) {
    const int t = threadIdx.x;
    const int wid  = t >> 6;
    const int lane = t & 63;
    const int col  = lane & 15;
    const int quad = lane >> 4;
    const int base = blockIdx.x * 128 + wid * 32;

    const size_t row0 = (size_t)tok[base + col];
    const size_t row1 = (size_t)tok[base + 16 + col];

    floatx4 acc[2][8] = {};

#pragma unroll
    for (int kc = 0; kc < DIN / 32; ++kc) {
        const int ko = kc * 32 + quad * 8;
        short8 a0 = *(const short8*)&Ab[row0 * DIN + ko];
        short8 a1 = *(const short8*)&Ab[row1 * DIN + ko];
#pragma unroll
        for (int ft = 0; ft < 8; ++ft) {
            short8 b = *(const short8*)&Wb[(size_t)(col * 8 + ft) * DIN + ko];
            acc[0][ft] = __builtin_amdgcn_mfma_f32_16x16x32_bf16(a0, b, acc[0][ft], 0, 0, 0);
            acc[1][ft] = __builtin_amdgcn_mfma_f32_16x16x32_bf16(a1, b, acc[1][ft], 0, 0, 0);
        }
    }

    const float4 bv0 = *(const float4*)&bias[col * 8];
    const float4 bv1 = *(const float4*)&bias[col * 8 + 4];
    const float bb[8] = {bv0.x, bv0.y, bv0.z, bv0.w, bv1.x, bv1.y, bv1.z, bv1.w};

#pragma unroll
    for (int mt = 0; mt < 2; ++mt) {
#pragma unroll
        for (int r = 0; r < 4; ++r) {
            const int row = base + mt * 16 + quad * 4 + r;
            short8 o;
#pragma unroll
            for (int ft = 0; ft < 8; ++ft)
                o[ft] = bf16_rne(acc[mt][ft][r] + bb[ft]);
            *(short8*)&out[(size_t)row * DHID + col * 8] = o;
        }
    }
}

// ---------------- fused GCN conv (degree-bucketed) ----------------
// One wave = 16 nodes taken from perm[] (counting-sorted by degree): all 16
// lanes have ~equal cnt -> trip count drops from E[max16 Poisson4]=9.3 to ~4.2
// and wave durations are uniform (no straggler drain).
// __launch_bounds__(256,8) pins VGPR<=64 -> 8 waves/SIMD (round-1 lesson:
// 68 VGPR halves occupancy at the 64-reg HW step).

template <bool RELU, bool OUT_BF16>
__global__ __launch_bounds__(256, 8) void fused_conv(const short* __restrict__ x,
                                                     const int2* __restrict__ csr,
                                                     const int* __restrict__ offsets,
                                                     const int* __restrict__ counts,
                                                     const float* __restrict__ dinv,
                                                     const int* __restrict__ perm,
                                                     const short* __restrict__ Wb,
                                                     const float* __restrict__ bias,
                                                     void* __restrict__ outp) {
    const int t = threadIdx.x;
    const int wid  = t >> 6;
    const int lane = t & 63;
    const int col  = lane & 15;
    const int quad = lane >> 4;
    const int base = (blockIdx.x * 4 + wid) * 16;
    const int node = perm[base + col];

    const float di = dinv[node];
    const int beg = offsets[node];
    const int cnt = counts[node];
    const int2* pcsr = csr + beg;

    // self-loop init: af = di * x_self   (total = di*(di*x_self + sum w_s*x_s))
    float af[4][8];
    {
        const size_t xrow = (size_t)node * DHID + quad * 8;
#pragma unroll
        for (int c = 0; c < 4; ++c) {
            short8 v = *(const short8*)&x[xrow + c * 32];
#pragma unroll
            for (int j = 0; j < 8; ++j) af[c][j] = di * bf16_to_f(v[j]);
        }
    }

    // edge loop: single edge/iter, packed-entry 1-ahead prefetch
    int2 cn = (cnt > 0) ? pcsr[0] : make_int2(0, 0);
    for (int e = 0; e < cnt; ++e) {
        const int   s = cn.x;
        const float w = __int_as_float(cn.y);
        if (e + 1 < cnt) cn = pcsr[e + 1];
        const size_t r0 = (size_t)s * DHID + quad * 8;
        short8 u0 = *(const short8*)&x[r0];
        short8 u1 = *(const short8*)&x[r0 + 32];
        short8 u2 = *(const short8*)&x[r0 + 64];
        short8 u3 = *(const short8*)&x[r0 + 96];
#pragma unroll
        for (int j = 0; j < 8; ++j) {
            af[0][j] = fmaf(w, bf16_to_f(u0[j]), af[0][j]);
            af[1][j] = fmaf(w, bf16_to_f(u1[j]), af[1][j]);
            af[2][j] = fmaf(w, bf16_to_f(u2[j]), af[2][j]);
            af[3][j] = fmaf(w, bf16_to_f(u3[j]), af[3][j]);
        }
    }

    // fold the outer di and round aggregated A-fragments to bf16
    short8 a[4];
#pragma unroll
    for (int c = 0; c < 4; ++c)
#pragma unroll
        for (int j = 0; j < 8; ++j) a[c][j] = bf16_rne(di * af[c][j]);

    // MFMA with weights (L1-hot). B-row remap (row = col*8+ft): lane's outputs
    // across ft are consecutive features -> 16B/32B contiguous stores.
    floatx4 acc[8] = {};
#pragma unroll
    for (int c = 0; c < 4; ++c) {
        const int ko = c * 32 + quad * 8;
#pragma unroll
        for (int ft = 0; ft < 8; ++ft) {
            short8 b = *(const short8*)&Wb[(size_t)(col * 8 + ft) * DHID + ko];
            acc[ft] = __builtin_amdgcn_mfma_f32_16x16x32_bf16(a[c], b, acc[ft], 0, 0, 0);
        }
    }

    // epilogue: D rows m=quad*4+r are nodes perm[base+quad*4+r]; features col*8..+7
    const float4 bv0 = *(const float4*)&bias[col * 8];
    const float4 bv1 = *(const float4*)&bias[col * 8 + 4];
    const float bb[8] = {bv0.x, bv0.y, bv0.z, bv0.w, bv1.x, bv1.y, bv1.z, bv1.w};
    const int4 pr = *(const int4*)&perm[base + quad * 4];
    const int prn[4] = {pr.x, pr.y, pr.z, pr.w};
    short* outb = (short*)outp;
    float* outf = (float*)outp;
#pragma unroll
    for (int r = 0; r < 4; ++r) {
        const size_t row = (size_t)prn[r] * DHID + col * 8;
        if (OUT_BF16) {
            short8 o;
#pragma unroll
            for (int ft = 0; ft < 8; ++ft) {
                float v = acc[ft][r] + bb[ft];
                if (RELU) v = fmaxf(v, 0.f);
                o[ft] = bf16_rne(v);
            }
            *(short8*)&outb[row] = o;
        } else {
            float4 o0, o1;
            o0.x = acc[0][r] + bb[0]; o0.y = acc[1][r] + bb[1];
            o0.z = acc[2][r] + bb[2]; o0.w = acc[3][r] + bb[3];
            o1.x = acc[4][r] + bb[4]; o1.y = acc[5][r] + bb[5];
            o1.z = acc[6][r] + bb[6]; o1.w = acc[7][r] + bb[7];
            if (RELU) {
                o0.x = fmaxf(o0.x, 0.f); o0.y = fmaxf(o0.y, 0.f);
                o0.z = fmaxf(o0.z, 0.f); o0.w = fmaxf(o0.w, 0.f);
                o1.x = fmaxf(o1.x, 0.f); o1.y = fmaxf(o1.y, 0.f);
                o1.z = fmaxf(o1.z, 0.f); o1.w = fmaxf(o1.w, 0.f);
            }
            *(float4*)&outf[row] = o0;
            *(float4*)&outf[row + 4] = o1;
        }
    }
}

// ---------------- metadata outputs ----------------

__global__ __launch_bounds__(256) void meta_kernel(const int* __restrict__ tok,
                                                   float* __restrict__ out) {
    int i = blockIdx.x * 256 + threadIdx.x;
    const size_t L0 = (size_t)N_NODES * DHID;
    out[L0 + i]               = (float)tok[i];
    out[L0 + N_NODES + i]     = 1.0f;
    out[L0 + 2 * N_NODES + i] = (float)(i & 2047);
}

// ---------------- launch ----------------

extern "C" void kernel_launch(void* const* d_in, const int* in_sizes, int n_in,
                              void* d_out, int out_size, void* d_ws, size_t ws_size,
                              hipStream_t stream) {
    const int*   tok  = (const int*)d_in[0];
    const int*   esrc = (const int*)d_in[1];
    const int*   edst = esrc + N_EDGES;
    const float* emb  = (const float*)d_in[2];
    const float* Wn   = (const float*)d_in[3];
    const float* bn   = (const float*)d_in[4];
    const float* W1   = (const float*)d_in[5];
    const float* b1   = (const float*)d_in[6];
    const float* W2   = (const float*)d_in[7];
    const float* b2   = (const float*)d_in[8];
    float* out = (float*)d_out;

    char* ws = (char*)d_ws;
    int*   counts  = (int*)(ws);                              // 512 KB @0
    int*   offsets = (int*)(ws + (1u << 19));                 // 512 KB @0.5MB
    int*   cursor  = (int*)(ws + (2u << 19));                 // 512 KB @1MB
    float* dinv    = (float*)(ws + (3u << 19));               // 512 KB @1.5MB
    int*   bsums   = (int*)(ws + (4u << 19));                 // 2 KB   @2MB
    int*   bhist   = (int*)(ws + (4u << 19) + 4096);          // 256 B  @2MB+4K
    int*   bcur    = (int*)(ws + (4u << 19) + 8192);          // 256 B  @2MB+8K
    int*   perm    = (int*)(ws + (5u << 19));                 // 512 KB @2.5MB
    int2*  csr     = (int2*)(ws + 3 * (1u << 20));            // 4 MB   @3MB
    short* Wnb     = (short*)(ws + 7 * (1u << 20));           // 64 KB  @7MB
    short* W1b     = (short*)(ws + 7 * (1u << 20) + (1u << 16)); // 32 KB
    short* W2b     = (short*)(ws + 7 * (1u << 20) + 96 * 1024);  // 32 KB
    short* embb    = (short*)(ws + 7 * (1u << 20) + (1u << 18)); // 16.4 MB @7.25MB
    short* x2b     = (short*)(ws + 24 * (1u << 20));          // 33.5 MB @24MB
    short* xb      = (short*)d_out;                           // 33.5 MB scratch in d_out

    hipMemsetAsync(counts, 0, N_NODES * sizeof(int), stream);
    hipMemsetAsync(bhist, 0, 8192, stream);                   // bhist + bcur
    count_edges<<<N_EDGES / 256, 256, 0, stream>>>(edst, counts);
    scan1<<<N_NODES / 256, 256, 0, stream>>>(counts, offsets, bsums);
    scan2<<<1, 512, 0, stream>>>(bsums);
    scan3<<<N_NODES / 256, 256, 0, stream>>>(counts, offsets, cursor, dinv, bsums, bhist);
    bucket_scan<<<1, 64, 0, stream>>>(bhist, bcur);
    bucket_scatter<<<N_NODES / 256, 256, 0, stream>>>(counts, bcur, perm);
    fill_csr<<<N_EDGES / 256, 256, 0, stream>>>(esrc, edst, cursor, dinv, csr);
    convert_weights<<<65536 / 256, 256, 0, stream>>>(Wn, W1, W2, Wnb, W1b, W2b);
    convert_emb<<<(32000 * 256 / 8) / 256, 256, 0, stream>>>(emb, embb);

    // x = bf16(embb[tok] @ Wn^T + bn) -> xb (d_out scratch)
    gemm_embed<<<N_NODES / 128, 256, 0, stream>>>(embb, tok, Wnb, bn, xb);
    // conv1: fused aggregate+GEMM, relu, bf16 out -> x2b
    fused_conv<true, true><<<N_NODES / 64, 256, 0, stream>>>(
        xb, csr, offsets, counts, dinv, perm, W1b, b1, x2b);
    // conv2: fused, fp32 out straight to d_out (overwrites xb scratch; reads only x2b)
    fused_conv<false, false><<<N_NODES / 64, 256, 0, stream>>>(
        x2b, csr, offsets, counts, dinv, perm, W2b, b2, out);

    meta_kernel<<<N_NODES / 256, 256, 0, stream>>>(tok, out);
}

// Round 3
// 358.718 us; speedup vs baseline: 3.9308x; 3.9308x over previous
//
#include <hip/hip_runtime.h>
#include <hip/hip_bf16.h>

#define N_NODES 131072
#define N_EDGES 524288
#define DHID    128
#define DIN     256

typedef __attribute__((ext_vector_type(8))) short short8;
typedef __attribute__((ext_vector_type(4))) float floatx4;

__device__ inline short bf16_rne(float f) {
    union { float f; unsigned u; } v; v.f = f;
    unsigned r = v.u + 0x7FFF + ((v.u >> 16) & 1);
    return (short)(r >> 16);
}
__device__ inline float bf16_to_f(short s) {
    union { unsigned u; float f; } v; v.u = ((unsigned)(unsigned short)s) << 16;
    return v.f;
}

// ---------------- CSR build ----------------

__global__ __launch_bounds__(256) void count_edges(const int* __restrict__ dst,
                                                   int* __restrict__ counts) {
    int e = blockIdx.x * 256 + threadIdx.x;
    atomicAdd(&counts[dst[e]], 1);
}

__global__ __launch_bounds__(256) void scan1(const int* __restrict__ counts,
                                             int* __restrict__ offsets,
                                             int* __restrict__ bsums) {
    __shared__ int s[256];
    int i = blockIdx.x * 256 + threadIdx.x;
    int v = counts[i];
    s[threadIdx.x] = v;
    __syncthreads();
    for (int d = 1; d < 256; d <<= 1) {
        int t = (threadIdx.x >= d) ? s[threadIdx.x - d] : 0;
        __syncthreads();
        s[threadIdx.x] += t;
        __syncthreads();
    }
    offsets[i] = s[threadIdx.x] - v;
    if (threadIdx.x == 255) bsums[blockIdx.x] = s[255];
}

__global__ __launch_bounds__(512) void scan2(int* __restrict__ bsums) {
    __shared__ int s[512];
    int v = bsums[threadIdx.x];
    s[threadIdx.x] = v;
    __syncthreads();
    for (int d = 1; d < 512; d <<= 1) {
        int t = (threadIdx.x >= d) ? s[threadIdx.x - d] : 0;
        __syncthreads();
        s[threadIdx.x] += t;
        __syncthreads();
    }
    bsums[threadIdx.x] = s[threadIdx.x] - v;
}

// scan3: finalize offsets/cursor/dinv AND histogram node degrees for bucketing.
// Histogram is LDS-aggregated per block -> ONE global atomic per bucket per
// block (round-2 lesson: 131072 device atomics on ~12 hot addrs = 531 us).
__global__ __launch_bounds__(256) void scan3(const int* __restrict__ counts,
                                             int* __restrict__ offsets,
                                             int* __restrict__ cursor,
                                             float* __restrict__ dinv,
                                             const int* __restrict__ bsums,
                                             int* __restrict__ bhist) {
    __shared__ int lh[64];
    if (threadIdx.x < 64) lh[threadIdx.x] = 0;
    __syncthreads();
    int i = blockIdx.x * 256 + threadIdx.x;
    int off = offsets[i] + bsums[blockIdx.x];
    offsets[i] = off;
    cursor[i]  = off;
    int c = counts[i];
    dinv[i] = rsqrtf((float)(c + 1));
    atomicAdd(&lh[c < 63 ? c : 63], 1);          // LDS atomic
    __syncthreads();
    if (threadIdx.x < 64) {
        int v = lh[threadIdx.x];
        if (v) atomicAdd(&bhist[threadIdx.x], v); // one global atomic/bucket/block
    }
}

// 64-bucket exclusive scan (one block, LDS)
__global__ __launch_bounds__(64) void bucket_scan(int* __restrict__ bhist,
                                                  int* __restrict__ bcur) {
    __shared__ int s[64];
    int v = bhist[threadIdx.x];
    s[threadIdx.x] = v;
    __syncthreads();
    for (int d = 1; d < 64; d <<= 1) {
        int t = (threadIdx.x >= d) ? s[threadIdx.x - d] : 0;
        __syncthreads();
        s[threadIdx.x] += t;
        __syncthreads();
    }
    bcur[threadIdx.x] = s[threadIdx.x] - v;
}

// counting-sort nodes by degree -> perm. LDS-aggregated: local rank via LDS
// atomic, one global atomic per bucket per block reserves the span.
// Intra-bucket order is arbitrary (only degree-grouping matters).
__global__ __launch_bounds__(256) void bucket_scatter(const int* __restrict__ counts,
                                                      int* __restrict__ bcur,
                                                      int* __restrict__ perm) {
    __shared__ int lh[64];
    __shared__ int lbase[64];
    if (threadIdx.x < 64) lh[threadIdx.x] = 0;
    __syncthreads();
    int i = blockIdx.x * 256 + threadIdx.x;
    int c = counts[i];
    c = c < 63 ? c : 63;
    int r = atomicAdd(&lh[c], 1);                 // LDS atomic -> local rank
    __syncthreads();
    if (threadIdx.x < 64) {
        int v = lh[threadIdx.x];
        lbase[threadIdx.x] = v ? atomicAdd(&bcur[threadIdx.x], v) : 0;
    }
    __syncthreads();
    perm[lbase[c] + r] = i;
}

// packed CSR entry: {src, bits(dinv[src])} — no dependent per-edge dinv gather
__global__ __launch_bounds__(256) void fill_csr(const int* __restrict__ src,
                                                const int* __restrict__ dst,
                                                int* __restrict__ cursor,
                                                const float* __restrict__ dinv,
                                                int2* __restrict__ csr) {
    int e = blockIdx.x * 256 + threadIdx.x;
    int d = dst[e];
    int s = src[e];
    int p = atomicAdd(&cursor[d], 1);
    csr[p] = make_int2(s, __float_as_int(dinv[s]));
}

// ---------------- fp32 -> bf16 conversions (once per call) ----------------

__global__ __launch_bounds__(256) void convert_weights(const float* __restrict__ Wn,
                                                       const float* __restrict__ W1,
                                                       const float* __restrict__ W2,
                                                       short* __restrict__ Wnb,
                                                       short* __restrict__ W1b,
                                                       short* __restrict__ W2b) {
    int i = blockIdx.x * 256 + threadIdx.x;          // 65536 total
    if (i < 32768)      Wnb[i] = bf16_rne(Wn[i]);
    else if (i < 49152) W1b[i - 32768] = bf16_rne(W1[i - 32768]);
    else                W2b[i - 49152] = bf16_rne(W2[i - 49152]);
}

__global__ __launch_bounds__(256) void convert_emb(const float* __restrict__ in,
                                                   short* __restrict__ outb) {
    size_t i = (size_t)(blockIdx.x * 256 + threadIdx.x) * 8;   // 32000*256 = 8192000
    float4 v0 = *(const float4*)&in[i];
    float4 v1 = *(const float4*)&in[i + 4];
    short8 o;
    o[0] = bf16_rne(v0.x); o[1] = bf16_rne(v0.y);
    o[2] = bf16_rne(v0.z); o[3] = bf16_rne(v0.w);
    o[4] = bf16_rne(v1.x); o[5] = bf16_rne(v1.y);
    o[6] = bf16_rne(v1.z); o[7] = bf16_rne(v1.w);
    *(short8*)&outb[i] = o;
}

// ---------------- embed GEMM: out[i][:] = embb[tok[i]] @ Wn^T + bn ----------------

__global__ __launch_bounds__(256) void gemm_embed(const short* __restrict__ Ab,
                                                  const int* __restrict__ tok,
                                                  const short* __restrict__ Wb,
                                                  const float* __restrict__ bias,
                                                  short* __restrict__ out) {
    const int t = threadIdx.x;
    const int wid  = t >> 6;
    const int lane = t & 63;
    const int col  = lane & 15;
    const int quad = lane >> 4;
    const int base = blockIdx.x * 128 + wid * 32;

    const size_t row0 = (size_t)tok[base + col];
    const size_t row1 = (size_t)tok[base + 16 + col];

    floatx4 acc[2][8] = {};

#pragma unroll
    for (int kc = 0; kc < DIN / 32; ++kc) {
        const int ko = kc * 32 + quad * 8;
        short8 a0 = *(const short8*)&Ab[row0 * DIN + ko];
        short8 a1 = *(const short8*)&Ab[row1 * DIN + ko];
#pragma unroll
        for (int ft = 0; ft < 8; ++ft) {
            short8 b = *(const short8*)&Wb[(size_t)(col * 8 + ft) * DIN + ko];
            acc[0][ft] = __builtin_amdgcn_mfma_f32_16x16x32_bf16(a0, b, acc[0][ft], 0, 0, 0);
            acc[1][ft] = __builtin_amdgcn_mfma_f32_16x16x32_bf16(a1, b, acc[1][ft], 0, 0, 0);
        }
    }

    const float4 bv0 = *(const float4*)&bias[col * 8];
    const float4 bv1 = *(const float4*)&bias[col * 8 + 4];
    const float bb[8] = {bv0.x, bv0.y, bv0.z, bv0.w, bv1.x, bv1.y, bv1.z, bv1.w};

#pragma unroll
    for (int mt = 0; mt < 2; ++mt) {
#pragma unroll
        for (int r = 0; r < 4; ++r) {
            const int row = base + mt * 16 + quad * 4 + r;
            short8 o;
#pragma unroll
            for (int ft = 0; ft < 8; ++ft)
                o[ft] = bf16_rne(acc[mt][ft][r] + bb[ft]);
            *(short8*)&out[(size_t)row * DHID + col * 8] = o;
        }
    }
}

// ---------------- fused GCN conv (degree-bucketed) ----------------
// One wave = 16 nodes taken from perm[] (counting-sorted by degree): all 16
// lanes have ~equal cnt -> trip count drops from E[max16 Poisson4]=9.3 to ~4.2
// and wave durations are uniform (no straggler drain).
// __launch_bounds__(256,8) pins VGPR<=64 -> 8 waves/SIMD.

template <bool RELU, bool OUT_BF16>
__global__ __launch_bounds__(256, 8) void fused_conv(const short* __restrict__ x,
                                                     const int2* __restrict__ csr,
                                                     const int* __restrict__ offsets,
                                                     const int* __restrict__ counts,
                                                     const float* __restrict__ dinv,
                                                     const int* __restrict__ perm,
                                                     const short* __restrict__ Wb,
                                                     const float* __restrict__ bias,
                                                     void* __restrict__ outp) {
    const int t = threadIdx.x;
    const int wid  = t >> 6;
    const int lane = t & 63;
    const int col  = lane & 15;
    const int quad = lane >> 4;
    const int base = (blockIdx.x * 4 + wid) * 16;
    const int node = perm[base + col];

    const float di = dinv[node];
    const int beg = offsets[node];
    const int cnt = counts[node];
    const int2* pcsr = csr + beg;

    // self-loop init: af = di * x_self   (total = di*(di*x_self + sum w_s*x_s))
    float af[4][8];
    {
        const size_t xrow = (size_t)node * DHID + quad * 8;
#pragma unroll
        for (int c = 0; c < 4; ++c) {
            short8 v = *(const short8*)&x[xrow + c * 32];
#pragma unroll
            for (int j = 0; j < 8; ++j) af[c][j] = di * bf16_to_f(v[j]);
        }
    }

    // edge loop: single edge/iter, packed-entry 1-ahead prefetch
    int2 cn = (cnt > 0) ? pcsr[0] : make_int2(0, 0);
    for (int e = 0; e < cnt; ++e) {
        const int   s = cn.x;
        const float w = __int_as_float(cn.y);
        if (e + 1 < cnt) cn = pcsr[e + 1];
        const size_t r0 = (size_t)s * DHID + quad * 8;
        short8 u0 = *(const short8*)&x[r0];
        short8 u1 = *(const short8*)&x[r0 + 32];
        short8 u2 = *(const short8*)&x[r0 + 64];
        short8 u3 = *(const short8*)&x[r0 + 96];
#pragma unroll
        for (int j = 0; j < 8; ++j) {
            af[0][j] = fmaf(w, bf16_to_f(u0[j]), af[0][j]);
            af[1][j] = fmaf(w, bf16_to_f(u1[j]), af[1][j]);
            af[2][j] = fmaf(w, bf16_to_f(u2[j]), af[2][j]);
            af[3][j] = fmaf(w, bf16_to_f(u3[j]), af[3][j]);
        }
    }

    // fold the outer di and round aggregated A-fragments to bf16
    short8 a[4];
#pragma unroll
    for (int c = 0; c < 4; ++c)
#pragma unroll
        for (int j = 0; j < 8; ++j) a[c][j] = bf16_rne(di * af[c][j]);

    // MFMA with weights (L1-hot). B-row remap (row = col*8+ft): lane's outputs
    // across ft are consecutive features -> 16B/32B contiguous stores.
    floatx4 acc[8] = {};
#pragma unroll
    for (int c = 0; c < 4; ++c) {
        const int ko = c * 32 + quad * 8;
#pragma unroll
        for (int ft = 0; ft < 8; ++ft) {
            short8 b = *(const short8*)&Wb[(size_t)(col * 8 + ft) * DHID + ko];
            acc[ft] = __builtin_amdgcn_mfma_f32_16x16x32_bf16(a[c], b, acc[ft], 0, 0, 0);
        }
    }

    // epilogue: D rows m=quad*4+r are nodes perm[base+quad*4+r]; features col*8..+7
    const float4 bv0 = *(const float4*)&bias[col * 8];
    const float4 bv1 = *(const float4*)&bias[col * 8 + 4];
    const float bb[8] = {bv0.x, bv0.y, bv0.z, bv0.w, bv1.x, bv1.y, bv1.z, bv1.w};
    const int4 pr = *(const int4*)&perm[base + quad * 4];
    const int prn[4] = {pr.x, pr.y, pr.z, pr.w};
    short* outb = (short*)outp;
    float* outf = (float*)outp;
#pragma unroll
    for (int r = 0; r < 4; ++r) {
        const size_t row = (size_t)prn[r] * DHID + col * 8;
        if (OUT_BF16) {
            short8 o;
#pragma unroll
            for (int ft = 0; ft < 8; ++ft) {
                float v = acc[ft][r] + bb[ft];
                if (RELU) v = fmaxf(v, 0.f);
                o[ft] = bf16_rne(v);
            }
            *(short8*)&outb[row] = o;
        } else {
            float4 o0, o1;
            o0.x = acc[0][r] + bb[0]; o0.y = acc[1][r] + bb[1];
            o0.z = acc[2][r] + bb[2]; o0.w = acc[3][r] + bb[3];
            o1.x = acc[4][r] + bb[4]; o1.y = acc[5][r] + bb[5];
            o1.z = acc[6][r] + bb[6]; o1.w = acc[7][r] + bb[7];
            if (RELU) {
                o0.x = fmaxf(o0.x, 0.f); o0.y = fmaxf(o0.y, 0.f);
                o0.z = fmaxf(o0.z, 0.f); o0.w = fmaxf(o0.w, 0.f);
                o1.x = fmaxf(o1.x, 0.f); o1.y = fmaxf(o1.y, 0.f);
                o1.z = fmaxf(o1.z, 0.f); o1.w = fmaxf(o1.w, 0.f);
            }
            *(float4*)&outf[row] = o0;
            *(float4*)&outf[row + 4] = o1;
        }
    }
}

// ---------------- metadata outputs ----------------

__global__ __launch_bounds__(256) void meta_kernel(const int* __restrict__ tok,
                                                   float* __restrict__ out) {
    int i = blockIdx.x * 256 + threadIdx.x;
    const size_t L0 = (size_t)N_NODES * DHID;
    out[L0 + i]               = (float)tok[i];
    out[L0 + N_NODES + i]     = 1.0f;
    out[L0 + 2 * N_NODES + i] = (float)(i & 2047);
}

// ---------------- launch ----------------

extern "C" void kernel_launch(void* const* d_in, const int* in_sizes, int n_in,
                              void* d_out, int out_size, void* d_ws, size_t ws_size,
                              hipStream_t stream) {
    const int*   tok  = (const int*)d_in[0];
    const int*   esrc = (const int*)d_in[1];
    const int*   edst = esrc + N_EDGES;
    const float* emb  = (const float*)d_in[2];
    const float* Wn   = (const float*)d_in[3];
    const float* bn   = (const float*)d_in[4];
    const float* W1   = (const float*)d_in[5];
    const float* b1   = (const float*)d_in[6];
    const float* W2   = (const float*)d_in[7];
    const float* b2   = (const float*)d_in[8];
    float* out = (float*)d_out;

    char* ws = (char*)d_ws;
    int*   counts  = (int*)(ws);                              // 512 KB @0
    int*   offsets = (int*)(ws + (1u << 19));                 // 512 KB @0.5MB
    int*   cursor  = (int*)(ws + (2u << 19));                 // 512 KB @1MB
    float* dinv    = (float*)(ws + (3u << 19));               // 512 KB @1.5MB
    int*   bsums   = (int*)(ws + (4u << 19));                 // 2 KB   @2MB
    int*   bhist   = (int*)(ws + (4u << 19) + 4096);          // 256 B  @2MB+4K
    int*   bcur    = (int*)(ws + (4u << 19) + 8192);          // 256 B  @2MB+8K
    int*   perm    = (int*)(ws + (5u << 19));                 // 512 KB @2.5MB
    int2*  csr     = (int2*)(ws + 3 * (1u << 20));            // 4 MB   @3MB
    short* Wnb     = (short*)(ws + 7 * (1u << 20));           // 64 KB  @7MB
    short* W1b     = (short*)(ws + 7 * (1u << 20) + (1u << 16)); // 32 KB
    short* W2b     = (short*)(ws + 7 * (1u << 20) + 96 * 1024);  // 32 KB
    short* embb    = (short*)(ws + 7 * (1u << 20) + (1u << 18)); // 16.4 MB @7.25MB
    short* x2b     = (short*)(ws + 24 * (1u << 20));          // 33.5 MB @24MB
    short* xb      = (short*)d_out;                           // 33.5 MB scratch in d_out

    hipMemsetAsync(counts, 0, N_NODES * sizeof(int), stream);
    hipMemsetAsync(bhist, 0, 8192, stream);                   // bhist + bcur
    count_edges<<<N_EDGES / 256, 256, 0, stream>>>(edst, counts);
    scan1<<<N_NODES / 256, 256, 0, stream>>>(counts, offsets, bsums);
    scan2<<<1, 512, 0, stream>>>(bsums);
    scan3<<<N_NODES / 256, 256, 0, stream>>>(counts, offsets, cursor, dinv, bsums, bhist);
    bucket_scan<<<1, 64, 0, stream>>>(bhist, bcur);
    bucket_scatter<<<N_NODES / 256, 256, 0, stream>>>(counts, bcur, perm);
    fill_csr<<<N_EDGES / 256, 256, 0, stream>>>(esrc, edst, cursor, dinv, csr);
    convert_weights<<<65536 / 256, 256, 0, stream>>>(Wn, W1, W2, Wnb, W1b, W2b);
    convert_emb<<<(32000 * 256 / 8) / 256, 256, 0, stream>>>(emb, embb);

    // x = bf16(embb[tok] @ Wn^T + bn) -> xb (d_out scratch)
    gemm_embed<<<N_NODES / 128, 256, 0, stream>>>(embb, tok, Wnb, bn, xb);
    // conv1: fused aggregate+GEMM, relu, bf16 out -> x2b
    fused_conv<true, true><<<N_NODES / 64, 256, 0, stream>>>(
        xb, csr, offsets, counts, dinv, perm, W1b, b1, x2b);
    // conv2: fused, fp32 out straight to d_out (overwrites xb scratch; reads only x2b)
    fused_conv<false, false><<<N_NODES / 64, 256, 0, stream>>>(
        x2b, csr, offsets, counts, dinv, perm, W2b, b2, out);

    meta_kernel<<<N_NODES / 256, 256, 0, stream>>>(tok, out);
}

// Round 4
// 336.921 us; speedup vs baseline: 4.1851x; 1.0647x over previous
//
#include <hip/hip_runtime.h>
#include <hip/hip_bf16.h>

#define N_NODES 131072
#define N_EDGES 524288
#define DHID    128
#define DIN     256

typedef __attribute__((ext_vector_type(8))) short short8;
typedef __attribute__((ext_vector_type(4))) float floatx4;

__device__ inline short bf16_rne(float f) {
    union { float f; unsigned u; } v; v.f = f;
    unsigned r = v.u + 0x7FFF + ((v.u >> 16) & 1);
    return (short)(r >> 16);
}
__device__ inline float bf16_to_f(short s) {
    union { unsigned u; float f; } v; v.u = ((unsigned)(unsigned short)s) << 16;
    return v.f;
}

// ---------------- mega prep: convert emb + convert weights + count edges ----------------
// Disjoint block ranges; merges 3 kernels into 1 launch (round-3 lesson: the
// ~215us non-conv tail is dominated by launch/serialization of many small kernels).

__global__ __launch_bounds__(256) void mega_prep(const float* __restrict__ emb,
                                                 short* __restrict__ embb,
                                                 const float* __restrict__ Wn,
                                                 const float* __restrict__ W1,
                                                 const float* __restrict__ W2,
                                                 short* __restrict__ Wnb,
                                                 short* __restrict__ W1b,
                                                 short* __restrict__ W2b,
                                                 const int* __restrict__ edst,
                                                 int* __restrict__ counts) {
    const int b = blockIdx.x;
    if (b < 4000) {                      // embed table fp32->bf16, 8 elems/thread
        size_t i = (size_t)(b * 256 + threadIdx.x) * 8;   // 32000*256 = 8192000
        float4 v0 = *(const float4*)&emb[i];
        float4 v1 = *(const float4*)&emb[i + 4];
        short8 o;
        o[0] = bf16_rne(v0.x); o[1] = bf16_rne(v0.y);
        o[2] = bf16_rne(v0.z); o[3] = bf16_rne(v0.w);
        o[4] = bf16_rne(v1.x); o[5] = bf16_rne(v1.y);
        o[6] = bf16_rne(v1.z); o[7] = bf16_rne(v1.w);
        *(short8*)&embb[i] = o;
    } else if (b < 4256) {               // weights fp32->bf16 (65536 elems)
        int i = (b - 4000) * 256 + threadIdx.x;
        if (i < 32768)      Wnb[i] = bf16_rne(Wn[i]);
        else if (i < 49152) W1b[i - 32768] = bf16_rne(W1[i - 32768]);
        else                W2b[i - 49152] = bf16_rne(W2[i - 49152]);
    } else {                             // count edge destinations (524288)
        int e = (b - 4256) * 256 + threadIdx.x;
        atomicAdd(&counts[edst[e]], 1);
    }
}

// ---------------- unordered CSR allocation ----------------
// CSR offsets need only be DISJOINT, not ordered: block-level LDS scan + one
// global atomicAdd per block for the base. Replaces scan1+scan2+scan3 (3
// launches incl. a serial 1-block kernel) with 1 launch.

__global__ __launch_bounds__(256) void alloc_csr(const int* __restrict__ counts,
                                                 int* __restrict__ offsets,
                                                 int* __restrict__ cursor,
                                                 float* __restrict__ dinv,
                                                 int* __restrict__ total) {
    __shared__ int s[256];
    __shared__ int base;
    int i = blockIdx.x * 256 + threadIdx.x;
    int v = counts[i];
    s[threadIdx.x] = v;
    __syncthreads();
    for (int d = 1; d < 256; d <<= 1) {
        int t = (threadIdx.x >= d) ? s[threadIdx.x - d] : 0;
        __syncthreads();
        s[threadIdx.x] += t;
        __syncthreads();
    }
    int incl = s[threadIdx.x];
    if (threadIdx.x == 255) base = atomicAdd(total, incl);  // block sum
    __syncthreads();
    int off = base + incl - v;
    offsets[i] = off;
    cursor[i]  = off;
    dinv[i] = rsqrtf((float)(v + 1));
}

// packed CSR entry: {src, bits(dinv[src])} — no dependent per-edge dinv gather
__global__ __launch_bounds__(256) void fill_csr(const int* __restrict__ src,
                                                const int* __restrict__ dst,
                                                int* __restrict__ cursor,
                                                const float* __restrict__ dinv,
                                                int2* __restrict__ csr) {
    int e = blockIdx.x * 256 + threadIdx.x;
    int d = dst[e];
    int s = src[e];
    int p = atomicAdd(&cursor[d], 1);
    csr[p] = make_int2(s, __float_as_int(dinv[s]));
}

// ---------------- embed GEMM: out[i][:] = embb[tok[i]] @ Wn^T + bn ----------------
// B-row remap (row = col*8+ft): lane's 8 outputs are consecutive features ->
// one short8 store per row. Metadata outputs folded in (reads tok anyway).

__global__ __launch_bounds__(256) void gemm_embed(const short* __restrict__ Ab,
                                                  const int* __restrict__ tok,
                                                  const short* __restrict__ Wb,
                                                  const float* __restrict__ bias,
                                                  short* __restrict__ out,
                                                  float* __restrict__ meta_out) {
    const int t = threadIdx.x;
    const int wid  = t >> 6;
    const int lane = t & 63;
    const int col  = lane & 15;
    const int quad = lane >> 4;
    const int base = blockIdx.x * 128 + wid * 32;

    // folded metadata: labels / mask / node ids for this block's 128 nodes
    if (t < 128) {
        int i = blockIdx.x * 128 + t;
        const size_t L0 = (size_t)N_NODES * DHID;
        meta_out[L0 + i]               = (float)tok[i];
        meta_out[L0 + N_NODES + i]     = 1.0f;
        meta_out[L0 + 2 * N_NODES + i] = (float)(i & 2047);
    }

    const size_t row0 = (size_t)tok[base + col];
    const size_t row1 = (size_t)tok[base + 16 + col];

    floatx4 acc[2][8] = {};

#pragma unroll
    for (int kc = 0; kc < DIN / 32; ++kc) {
        const int ko = kc * 32 + quad * 8;
        short8 a0 = *(const short8*)&Ab[row0 * DIN + ko];
        short8 a1 = *(const short8*)&Ab[row1 * DIN + ko];
#pragma unroll
        for (int ft = 0; ft < 8; ++ft) {
            short8 b = *(const short8*)&Wb[(size_t)(col * 8 + ft) * DIN + ko];
            acc[0][ft] = __builtin_amdgcn_mfma_f32_16x16x32_bf16(a0, b, acc[0][ft], 0, 0, 0);
            acc[1][ft] = __builtin_amdgcn_mfma_f32_16x16x32_bf16(a1, b, acc[1][ft], 0, 0, 0);
        }
    }

    const float4 bv0 = *(const float4*)&bias[col * 8];
    const float4 bv1 = *(const float4*)&bias[col * 8 + 4];
    const float bb[8] = {bv0.x, bv0.y, bv0.z, bv0.w, bv1.x, bv1.y, bv1.z, bv1.w};

#pragma unroll
    for (int mt = 0; mt < 2; ++mt) {
#pragma unroll
        for (int r = 0; r < 4; ++r) {
            const int row = base + mt * 16 + quad * 4 + r;
            short8 o;
#pragma unroll
            for (int ft = 0; ft < 8; ++ft)
                o[ft] = bf16_rne(acc[mt][ft][r] + bb[ft]);
            *(short8*)&out[(size_t)row * DHID + col * 8] = o;
        }
    }
}

// ---------------- fused GCN conv ----------------
// One wave = 16 nodes (identity order: round-3 A/B showed degree-bucketing is
// traffic-negative and time-neutral — the gather is throughput-walled at
// ~2.3 TB/s at the TCC boundary, not straggler-bound).
// __launch_bounds__(256,8) pins VGPR<=64 -> 8 waves/SIMD (62% occupancy, +8% BW).

template <bool RELU, bool OUT_BF16>
__global__ __launch_bounds__(256, 8) void fused_conv(const short* __restrict__ x,
                                                     const int2* __restrict__ csr,
                                                     const int* __restrict__ offsets,
                                                     const int* __restrict__ counts,
                                                     const float* __restrict__ dinv,
                                                     const short* __restrict__ Wb,
                                                     const float* __restrict__ bias,
                                                     void* __restrict__ outp) {
    const int t = threadIdx.x;
    const int wid  = t >> 6;
    const int lane = t & 63;
    const int col  = lane & 15;
    const int quad = lane >> 4;
    const int base = (blockIdx.x * 4 + wid) * 16;
    const int node = base + col;

    const float di = dinv[node];
    const int beg = offsets[node];
    const int cnt = counts[node];
    const int2* pcsr = csr + beg;

    // self-loop init: af = di * x_self   (total = di*(di*x_self + sum w_s*x_s))
    float af[4][8];
    {
        const size_t xrow = (size_t)node * DHID + quad * 8;
#pragma unroll
        for (int c = 0; c < 4; ++c) {
            short8 v = *(const short8*)&x[xrow + c * 32];
#pragma unroll
            for (int j = 0; j < 8; ++j) af[c][j] = di * bf16_to_f(v[j]);
        }
    }

    // edge loop: single edge/iter, packed-entry 1-ahead prefetch
    int2 cn = (cnt > 0) ? pcsr[0] : make_int2(0, 0);
    for (int e = 0; e < cnt; ++e) {
        const int   s = cn.x;
        const float w = __int_as_float(cn.y);
        if (e + 1 < cnt) cn = pcsr[e + 1];
        const size_t r0 = (size_t)s * DHID + quad * 8;
        short8 u0 = *(const short8*)&x[r0];
        short8 u1 = *(const short8*)&x[r0 + 32];
        short8 u2 = *(const short8*)&x[r0 + 64];
        short8 u3 = *(const short8*)&x[r0 + 96];
#pragma unroll
        for (int j = 0; j < 8; ++j) {
            af[0][j] = fmaf(w, bf16_to_f(u0[j]), af[0][j]);
            af[1][j] = fmaf(w, bf16_to_f(u1[j]), af[1][j]);
            af[2][j] = fmaf(w, bf16_to_f(u2[j]), af[2][j]);
            af[3][j] = fmaf(w, bf16_to_f(u3[j]), af[3][j]);
        }
    }

    // fold the outer di and round aggregated A-fragments to bf16
    short8 a[4];
#pragma unroll
    for (int c = 0; c < 4; ++c)
#pragma unroll
        for (int j = 0; j < 8; ++j) a[c][j] = bf16_rne(di * af[c][j]);

    // MFMA with weights (L1-hot). B-row remap (row = col*8+ft): lane's outputs
    // across ft are consecutive features -> 16B/32B contiguous stores.
    floatx4 acc[8] = {};
#pragma unroll
    for (int c = 0; c < 4; ++c) {
        const int ko = c * 32 + quad * 8;
#pragma unroll
        for (int ft = 0; ft < 8; ++ft) {
            short8 b = *(const short8*)&Wb[(size_t)(col * 8 + ft) * DHID + ko];
            acc[ft] = __builtin_amdgcn_mfma_f32_16x16x32_bf16(a[c], b, acc[ft], 0, 0, 0);
        }
    }

    // epilogue: D rows m=quad*4+r are nodes base+quad*4+r; features col*8..+7
    const float4 bv0 = *(const float4*)&bias[col * 8];
    const float4 bv1 = *(const float4*)&bias[col * 8 + 4];
    const float bb[8] = {bv0.x, bv0.y, bv0.z, bv0.w, bv1.x, bv1.y, bv1.z, bv1.w};
    short* outb = (short*)outp;
    float* outf = (float*)outp;
#pragma unroll
    for (int r = 0; r < 4; ++r) {
        const size_t row = (size_t)(base + quad * 4 + r) * DHID + col * 8;
        if (OUT_BF16) {
            short8 o;
#pragma unroll
            for (int ft = 0; ft < 8; ++ft) {
                float v = acc[ft][r] + bb[ft];
                if (RELU) v = fmaxf(v, 0.f);
                o[ft] = bf16_rne(v);
            }
            *(short8*)&outb[row] = o;
        } else {
            float4 o0, o1;
            o0.x = acc[0][r] + bb[0]; o0.y = acc[1][r] + bb[1];
            o0.z = acc[2][r] + bb[2]; o0.w = acc[3][r] + bb[3];
            o1.x = acc[4][r] + bb[4]; o1.y = acc[5][r] + bb[5];
            o1.z = acc[6][r] + bb[6]; o1.w = acc[7][r] + bb[7];
            if (RELU) {
                o0.x = fmaxf(o0.x, 0.f); o0.y = fmaxf(o0.y, 0.f);
                o0.z = fmaxf(o0.z, 0.f); o0.w = fmaxf(o0.w, 0.f);
                o1.x = fmaxf(o1.x, 0.f); o1.y = fmaxf(o1.y, 0.f);
                o1.z = fmaxf(o1.z, 0.f); o1.w = fmaxf(o1.w, 0.f);
            }
            *(float4*)&outf[row] = o0;
            *(float4*)&outf[row + 4] = o1;
        }
    }
}

// ---------------- launch ----------------

extern "C" void kernel_launch(void* const* d_in, const int* in_sizes, int n_in,
                              void* d_out, int out_size, void* d_ws, size_t ws_size,
                              hipStream_t stream) {
    const int*   tok  = (const int*)d_in[0];
    const int*   esrc = (const int*)d_in[1];
    const int*   edst = esrc + N_EDGES;
    const float* emb  = (const float*)d_in[2];
    const float* Wn   = (const float*)d_in[3];
    const float* bn   = (const float*)d_in[4];
    const float* W1   = (const float*)d_in[5];
    const float* b1   = (const float*)d_in[6];
    const float* W2   = (const float*)d_in[7];
    const float* b2   = (const float*)d_in[8];
    float* out = (float*)d_out;

    char* ws = (char*)d_ws;
    int*   counts  = (int*)(ws);                              // 512 KB @0
    int*   total   = (int*)(ws + (1u << 19));                 // 64 B   @0.5MB (zeroed w/ counts)
    int*   offsets = (int*)(ws + (1u << 19) + 256);           // 512 KB
    int*   cursor  = (int*)(ws + (2u << 19) + 256);           // 512 KB
    float* dinv    = (float*)(ws + (3u << 19) + 256);         // 512 KB
    int2*  csr     = (int2*)(ws + 3 * (1u << 20));            // 4 MB   @3MB
    short* Wnb     = (short*)(ws + 7 * (1u << 20));           // 64 KB  @7MB
    short* W1b     = (short*)(ws + 7 * (1u << 20) + (1u << 16)); // 32 KB
    short* W2b     = (short*)(ws + 7 * (1u << 20) + 96 * 1024);  // 32 KB
    short* embb    = (short*)(ws + 7 * (1u << 20) + (1u << 18)); // 16.4 MB @7.25MB
    short* x2b     = (short*)(ws + 24 * (1u << 20));          // 33.5 MB @24MB
    short* xb      = (short*)d_out;                           // 33.5 MB scratch in d_out

    // one memset covers counts (512 KB) + total counter
    hipMemsetAsync(counts, 0, (1u << 19) + 256, stream);
    // convert emb + convert weights + count edges (1 launch, disjoint block ranges)
    mega_prep<<<4256 + N_EDGES / 256, 256, 0, stream>>>(
        emb, embb, Wn, W1, W2, Wnb, W1b, W2b, edst, counts);
    // unordered CSR allocation (replaces 3-kernel ordered scan)
    alloc_csr<<<N_NODES / 256, 256, 0, stream>>>(counts, offsets, cursor, dinv, total);
    fill_csr<<<N_EDGES / 256, 256, 0, stream>>>(esrc, edst, cursor, dinv, csr);

    // x = bf16(embb[tok] @ Wn^T + bn) -> xb (d_out scratch); metadata folded in
    gemm_embed<<<N_NODES / 128, 256, 0, stream>>>(embb, tok, Wnb, bn, xb, out);
    // conv1: fused aggregate+GEMM, relu, bf16 out -> x2b
    fused_conv<true, true><<<N_NODES / 64, 256, 0, stream>>>(
        xb, csr, offsets, counts, dinv, W1b, b1, x2b);
    // conv2: fused, fp32 out straight to d_out (overwrites xb scratch; reads only x2b)
    fused_conv<false, false><<<N_NODES / 64, 256, 0, stream>>>(
        x2b, csr, offsets, counts, dinv, W2b, b2, out);
}

// Round 5
// 286.830 us; speedup vs baseline: 4.9160x; 1.1746x over previous
//
#include <hip/hip_runtime.h>
#include <hip/hip_bf16.h>

#define N_NODES 131072
#define N_EDGES 524288
#define DHID    128
#define DIN     256
#define VOCAB   32000

typedef __attribute__((ext_vector_type(8))) short short8;
typedef __attribute__((ext_vector_type(4))) float floatx4;

__device__ inline short bf16_rne(float f) {
    union { float f; unsigned u; } v; v.f = f;
    unsigned r = v.u + 0x7FFF + ((v.u >> 16) & 1);
    return (short)(r >> 16);
}
__device__ inline float bf16_to_f(short s) {
    union { unsigned u; float f; } v; v.u = ((unsigned)(unsigned short)s) << 16;
    return v.f;
}
__device__ inline short8 cvt8(float4 lo, float4 hi) {
    short8 o;
    o[0] = bf16_rne(lo.x); o[1] = bf16_rne(lo.y);
    o[2] = bf16_rne(lo.z); o[3] = bf16_rne(lo.w);
    o[4] = bf16_rne(hi.x); o[5] = bf16_rne(hi.y);
    o[6] = bf16_rne(hi.z); o[7] = bf16_rne(hi.w);
    return o;
}

// ---------------- mega: vocab GEMM + weight convert + edge count (1 launch) ----
// Block ranges:
//   [0,250)        z[v] = bf16(emb[v] @ Wn^T), v in vocab space (32000 rows).
//                  Dense STREAMING gemm — replaces the 131072-row random-gather
//                  gemm_embed (round-4 lesson: gather working-set size is the
//                  lever; x0 = z[tok] + bn has only 32000 distinct rows).
//   [250,378)      W1/W2 fp32->bf16 (32768 elems)
//   [378,2426)     count edge destinations

#define MEGA_VB 250
#define MEGA_WB 128
#define MEGA_TOTAL (MEGA_VB + MEGA_WB + N_EDGES / 256)

__global__ __launch_bounds__(256) void mega(const float* __restrict__ emb,
                                            const float* __restrict__ Wn,
                                            short* __restrict__ z,
                                            const float* __restrict__ W1,
                                            const float* __restrict__ W2,
                                            short* __restrict__ W1b,
                                            short* __restrict__ W2b,
                                            const int* __restrict__ edst,
                                            int* __restrict__ counts) {
    const int b = blockIdx.x;
    if (b < MEGA_VB) {
        // vocab GEMM, 128 rows/block, fp32 inputs converted in-reg (no Wnb/embb)
        const int t = threadIdx.x;
        const int wid  = t >> 6;
        const int lane = t & 63;
        const int col  = lane & 15;
        const int quad = lane >> 4;
        const int vbase = b * 128 + wid * 32;
        const size_t row0 = (size_t)(vbase + col);
        const size_t row1 = (size_t)(vbase + 16 + col);

        floatx4 acc[2][8] = {};
#pragma unroll
        for (int kc = 0; kc < DIN / 32; ++kc) {
            const int ko = kc * 32 + quad * 8;
            short8 a0 = cvt8(*(const float4*)&emb[row0 * DIN + ko],
                             *(const float4*)&emb[row0 * DIN + ko + 4]);
            short8 a1 = cvt8(*(const float4*)&emb[row1 * DIN + ko],
                             *(const float4*)&emb[row1 * DIN + ko + 4]);
#pragma unroll
            for (int ft = 0; ft < 8; ++ft) {
                const size_t wr = (size_t)(col * 8 + ft) * DIN + ko;
                short8 bb = cvt8(*(const float4*)&Wn[wr],
                                 *(const float4*)&Wn[wr + 4]);
                acc[0][ft] = __builtin_amdgcn_mfma_f32_16x16x32_bf16(a0, bb, acc[0][ft], 0, 0, 0);
                acc[1][ft] = __builtin_amdgcn_mfma_f32_16x16x32_bf16(a1, bb, acc[1][ft], 0, 0, 0);
            }
        }
        // NO bias here: bn is folded into conv1 via the sw scalar.
#pragma unroll
        for (int mt = 0; mt < 2; ++mt) {
#pragma unroll
            for (int r = 0; r < 4; ++r) {
                const int row = vbase + mt * 16 + quad * 4 + r;
                short8 o;
#pragma unroll
                for (int ft = 0; ft < 8; ++ft)
                    o[ft] = bf16_rne(acc[mt][ft][r]);
                *(short8*)&z[(size_t)row * DHID + col * 8] = o;
            }
        }
    } else if (b < MEGA_VB + MEGA_WB) {
        int i = (b - MEGA_VB) * 256 + threadIdx.x;     // 32768 total
        if (i < 16384) W1b[i] = bf16_rne(W1[i]);
        else           W2b[i - 16384] = bf16_rne(W2[i - 16384]);
    } else {
        int e = (b - MEGA_VB - MEGA_WB) * 256 + threadIdx.x;
        atomicAdd(&counts[edst[e]], 1);
    }
}

// ---------------- unordered CSR allocation + metadata outputs ----------------
// CSR offsets need only be DISJOINT, not ordered: block LDS scan + one global
// atomicAdd per block. Metadata folded in (this kernel spans exactly N_NODES).

__global__ __launch_bounds__(256) void alloc_csr(const int* __restrict__ counts,
                                                 int* __restrict__ offsets,
                                                 int* __restrict__ cursor,
                                                 float* __restrict__ dinv,
                                                 int* __restrict__ total,
                                                 const int* __restrict__ tok,
                                                 float* __restrict__ meta_out) {
    __shared__ int s[256];
    __shared__ int base;
    int i = blockIdx.x * 256 + threadIdx.x;
    int v = counts[i];
    s[threadIdx.x] = v;
    __syncthreads();
    for (int d = 1; d < 256; d <<= 1) {
        int t = (threadIdx.x >= d) ? s[threadIdx.x - d] : 0;
        __syncthreads();
        s[threadIdx.x] += t;
        __syncthreads();
    }
    int incl = s[threadIdx.x];
    if (threadIdx.x == 255) base = atomicAdd(total, incl);
    __syncthreads();
    int off = base + incl - v;
    offsets[i] = off;
    cursor[i]  = off;
    dinv[i] = rsqrtf((float)(v + 1));

    const size_t L0 = (size_t)N_NODES * DHID;
    meta_out[L0 + i]               = (float)tok[i];
    meta_out[L0 + N_NODES + i]     = 1.0f;
    meta_out[L0 + 2 * N_NODES + i] = (float)(i & 2047);
}

// packed CSR entry: int4 {src, tok[src], bits(dinv[src]), 0} — one 16B store
// (half the scattered-store line traffic of two 8B stores), serves both convs.
__global__ __launch_bounds__(256) void fill_csr(const int* __restrict__ src,
                                                const int* __restrict__ dst,
                                                int* __restrict__ cursor,
                                                const float* __restrict__ dinv,
                                                const int* __restrict__ tok,
                                                int4* __restrict__ csr) {
    int e = blockIdx.x * 256 + threadIdx.x;
    int d = dst[e];
    int s = src[e];
    int p = atomicAdd(&cursor[d], 1);
    csr[p] = make_int4(s, tok[s], __float_as_int(dinv[s]), 0);
}

// ---------------- fused GCN conv ----------------
// ZG (conv1): gather from the 7.8MB vocab table z via tok index (CSR .y) —
//   4.3x smaller gather working set than the materialized x0; input-bias bn
//   folded exactly via sw = di + sum(w):  A = di*(af + sw*bn).
// !ZG (conv2): gather from x (node-indexed, CSR .x), standard path.
// __launch_bounds__(256,8): VGPR<=64, 8 waves/SIMD.

template <bool RELU, bool OUT_BF16, bool ZG>
__global__ __launch_bounds__(256, 8) void fused_conv(const short* __restrict__ x,
                                                     const int4* __restrict__ csr,
                                                     const int* __restrict__ offsets,
                                                     const int* __restrict__ counts,
                                                     const float* __restrict__ dinv,
                                                     const int* __restrict__ tok,
                                                     const float* __restrict__ bn,
                                                     const short* __restrict__ Wb,
                                                     const float* __restrict__ bias,
                                                     void* __restrict__ outp) {
    const int t = threadIdx.x;
    const int wid  = t >> 6;
    const int lane = t & 63;
    const int col  = lane & 15;
    const int quad = lane >> 4;
    const int base = (blockIdx.x * 4 + wid) * 16;
    const int node = base + col;

    const float di = dinv[node];
    const int beg = offsets[node];
    const int cnt = counts[node];
    const int4* pcsr = csr + beg;

    // self-loop init: af = di * row_self
    float af[4][8];
    {
        const int self = ZG ? tok[node] : node;
        const size_t xrow = (size_t)self * DHID + quad * 8;
#pragma unroll
        for (int c = 0; c < 4; ++c) {
            short8 v = *(const short8*)&x[xrow + c * 32];
#pragma unroll
            for (int j = 0; j < 8; ++j) af[c][j] = di * bf16_to_f(v[j]);
        }
    }
    float sw = di;   // ZG only: running sum of norms for exact bn fold

    // edge loop: single edge/iter, packed-entry 1-ahead prefetch
    int4 cn = (cnt > 0) ? pcsr[0] : make_int4(0, 0, 0, 0);
    for (int e = 0; e < cnt; ++e) {
        const int   s = ZG ? cn.y : cn.x;
        const float w = __int_as_float(cn.z);
        if (e + 1 < cnt) cn = pcsr[e + 1];
        if (ZG) sw += w;
        const size_t r0 = (size_t)s * DHID + quad * 8;
        short8 u0 = *(const short8*)&x[r0];
        short8 u1 = *(const short8*)&x[r0 + 32];
        short8 u2 = *(const short8*)&x[r0 + 64];
        short8 u3 = *(const short8*)&x[r0 + 96];
#pragma unroll
        for (int j = 0; j < 8; ++j) {
            af[0][j] = fmaf(w, bf16_to_f(u0[j]), af[0][j]);
            af[1][j] = fmaf(w, bf16_to_f(u1[j]), af[1][j]);
            af[2][j] = fmaf(w, bf16_to_f(u2[j]), af[2][j]);
            af[3][j] = fmaf(w, bf16_to_f(u3[j]), af[3][j]);
        }
    }

    // fold outer di (+ sw*bn for ZG) and round A-fragments to bf16
    short8 a[4];
#pragma unroll
    for (int c = 0; c < 4; ++c) {
        if (ZG) {
            const float4 b0 = *(const float4*)&bn[c * 32 + quad * 8];
            const float4 b1 = *(const float4*)&bn[c * 32 + quad * 8 + 4];
            const float bv[8] = {b0.x, b0.y, b0.z, b0.w, b1.x, b1.y, b1.z, b1.w};
#pragma unroll
            for (int j = 0; j < 8; ++j)
                a[c][j] = bf16_rne(di * (af[c][j] + sw * bv[j]));
        } else {
#pragma unroll
            for (int j = 0; j < 8; ++j) a[c][j] = bf16_rne(di * af[c][j]);
        }
    }

    // MFMA with weights (L1-hot). B-row remap (row = col*8+ft): lane's outputs
    // across ft are consecutive features -> 16B/32B contiguous stores.
    floatx4 acc[8] = {};
#pragma unroll
    for (int c = 0; c < 4; ++c) {
        const int ko = c * 32 + quad * 8;
#pragma unroll
        for (int ft = 0; ft < 8; ++ft) {
            short8 b = *(const short8*)&Wb[(size_t)(col * 8 + ft) * DHID + ko];
            acc[ft] = __builtin_amdgcn_mfma_f32_16x16x32_bf16(a[c], b, acc[ft], 0, 0, 0);
        }
    }

    // epilogue: D rows m=quad*4+r are nodes base+quad*4+r; features col*8..+7
    const float4 bv0 = *(const float4*)&bias[col * 8];
    const float4 bv1 = *(const float4*)&bias[col * 8 + 4];
    const float bb[8] = {bv0.x, bv0.y, bv0.z, bv0.w, bv1.x, bv1.y, bv1.z, bv1.w};
    short* outb = (short*)outp;
    float* outf = (float*)outp;
#pragma unroll
    for (int r = 0; r < 4; ++r) {
        const size_t row = (size_t)(base + quad * 4 + r) * DHID + col * 8;
        if (OUT_BF16) {
            short8 o;
#pragma unroll
            for (int ft = 0; ft < 8; ++ft) {
                float v = acc[ft][r] + bb[ft];
                if (RELU) v = fmaxf(v, 0.f);
                o[ft] = bf16_rne(v);
            }
            *(short8*)&outb[row] = o;
        } else {
            float4 o0, o1;
            o0.x = acc[0][r] + bb[0]; o0.y = acc[1][r] + bb[1];
            o0.z = acc[2][r] + bb[2]; o0.w = acc[3][r] + bb[3];
            o1.x = acc[4][r] + bb[4]; o1.y = acc[5][r] + bb[5];
            o1.z = acc[6][r] + bb[6]; o1.w = acc[7][r] + bb[7];
            if (RELU) {
                o0.x = fmaxf(o0.x, 0.f); o0.y = fmaxf(o0.y, 0.f);
                o0.z = fmaxf(o0.z, 0.f); o0.w = fmaxf(o0.w, 0.f);
                o1.x = fmaxf(o1.x, 0.f); o1.y = fmaxf(o1.y, 0.f);
                o1.z = fmaxf(o1.z, 0.f); o1.w = fmaxf(o1.w, 0.f);
            }
            *(float4*)&outf[row] = o0;
            *(float4*)&outf[row + 4] = o1;
        }
    }
}

// ---------------- launch ----------------

extern "C" void kernel_launch(void* const* d_in, const int* in_sizes, int n_in,
                              void* d_out, int out_size, void* d_ws, size_t ws_size,
                              hipStream_t stream) {
    const int*   tok  = (const int*)d_in[0];
    const int*   esrc = (const int*)d_in[1];
    const int*   edst = esrc + N_EDGES;
    const float* emb  = (const float*)d_in[2];
    const float* Wn   = (const float*)d_in[3];
    const float* bn   = (const float*)d_in[4];
    const float* W1   = (const float*)d_in[5];
    const float* b1   = (const float*)d_in[6];
    const float* W2   = (const float*)d_in[7];
    const float* b2   = (const float*)d_in[8];
    float* out = (float*)d_out;

    char* ws = (char*)d_ws;
    int*   counts  = (int*)(ws);                              // 512 KB @0
    int*   total   = (int*)(ws + (1u << 19));                 // 256 B  @0.5MB (zeroed w/ counts)
    int*   offsets = (int*)(ws + (1u << 19) + 256);           // 512 KB
    int*   cursor  = (int*)(ws + (2u << 19) + 256);           // 512 KB
    float* dinv    = (float*)(ws + (3u << 19) + 256);         // 512 KB
    int4*  csr     = (int4*)(ws + 3 * (1u << 20));            // 8 MB   @3MB
    short* W1b     = (short*)(ws + 11 * (1u << 20));          // 32 KB  @11MB
    short* W2b     = (short*)(ws + 11 * (1u << 20) + (1u << 15)); // 32 KB
    short* z       = (short*)(ws + 12 * (1u << 20));          // 7.8 MB @12MB (32000*128*2)
    short* x2b     = (short*)(ws + 24 * (1u << 20));          // 33.5 MB @24MB

    // one memset covers counts (512 KB) + total counter
    hipMemsetAsync(counts, 0, (1u << 19) + 256, stream);
    // vocab GEMM + weight convert + edge count (1 launch, disjoint block ranges)
    mega<<<MEGA_TOTAL, 256, 0, stream>>>(emb, Wn, z, W1, W2, W1b, W2b, edst, counts);
    // unordered CSR allocation + metadata
    alloc_csr<<<N_NODES / 256, 256, 0, stream>>>(counts, offsets, cursor, dinv,
                                                 total, tok, out);
    fill_csr<<<N_EDGES / 256, 256, 0, stream>>>(esrc, edst, cursor, dinv, tok, csr);

    // conv1: z-gather (tok-indexed, 7.8MB working set) + exact bn fold, relu -> x2b
    fused_conv<true, true, true><<<N_NODES / 64, 256, 0, stream>>>(
        z, csr, offsets, counts, dinv, tok, bn, W1b, b1, x2b);
    // conv2: node-indexed gather from x2b, fp32 out straight to d_out
    fused_conv<false, false, false><<<N_NODES / 64, 256, 0, stream>>>(
        x2b, csr, offsets, counts, dinv, tok, bn, W2b, b2, out);
}